// Round 1
// baseline (1181.259 us; speedup 1.0000x reference)
//
#include <hip/hip_runtime.h>
#include <hip/hip_bf16.h>
#include <math.h>

// ---------------------------------------------------------------------------
// PairClassifier: projections -> masked 4-head cross attention -> MLP+LN ->
// segment-mean pool -> 3-way classifier.  All f32 (correctness baseline).
// ---------------------------------------------------------------------------

#define NP_N 4096
#define NH_N 4096
#define D_N 512
#define BERT_N 768
#define H_N 4
#define ATN_N 128
#define VH_N 192   // 768/4
#define B_N 32

// ----------------------- generic tiled f32 GEMM + bias ---------------------
// C[M][N] = A[M][K] @ W[K][N] + b[N]
// mode 0: plain row-major store
// mode 1: head-deinterleave store for Q/K: col n -> (h=n&3, d=n>>2),
//         C laid out as [H][M][128]
__global__ __launch_bounds__(256) void gemm_bias(
    const float* __restrict__ A, const float* __restrict__ W,
    const float* __restrict__ bias, float* __restrict__ C,
    int M, int N, int K, int mode)
{
    __shared__ float As[64][20];   // [m][k] padded
    __shared__ float Ws[16][64];   // [k][n]
    const int t = threadIdx.x;
    const int tx = t & 15, ty = t >> 4;
    const int m0 = blockIdx.y * 64, n0 = blockIdx.x * 64;

    float c[4][4] = {};
    for (int k0 = 0; k0 < K; k0 += 16) {
        __syncthreads();
#pragma unroll
        for (int l = 0; l < 4; l++) {
            int idx = t + l * 256;
            int m = idx >> 4, kk = idx & 15;
            As[m][kk] = A[(size_t)(m0 + m) * K + k0 + kk];
        }
#pragma unroll
        for (int l = 0; l < 4; l++) {
            int idx = t + l * 256;
            int kk = idx >> 6, n = idx & 63;
            Ws[kk][n] = W[(size_t)(k0 + kk) * N + n0 + n];
        }
        __syncthreads();
#pragma unroll
        for (int k4 = 0; k4 < 4; k4++) {
            float4 a4[4], w4[4];
#pragma unroll
            for (int i = 0; i < 4; i++) a4[i] = *(const float4*)&As[ty * 4 + i][k4 * 4];
#pragma unroll
            for (int kk = 0; kk < 4; kk++) w4[kk] = *(const float4*)&Ws[k4 * 4 + kk][tx * 4];
#pragma unroll
            for (int i = 0; i < 4; i++) {
                const float a0 = a4[i].x, a1 = a4[i].y, a2 = a4[i].z, a3 = a4[i].w;
                c[i][0] += a0 * w4[0].x + a1 * w4[1].x + a2 * w4[2].x + a3 * w4[3].x;
                c[i][1] += a0 * w4[0].y + a1 * w4[1].y + a2 * w4[2].y + a3 * w4[3].y;
                c[i][2] += a0 * w4[0].z + a1 * w4[1].z + a2 * w4[2].z + a3 * w4[3].z;
                c[i][3] += a0 * w4[0].w + a1 * w4[1].w + a2 * w4[2].w + a3 * w4[3].w;
            }
        }
    }
#pragma unroll
    for (int i = 0; i < 4; i++) {
        int m = m0 + ty * 4 + i;
#pragma unroll
        for (int j = 0; j < 4; j++) {
            int n = n0 + tx * 4 + j;
            float v = c[i][j] + bias[n];
            if (mode == 0) {
                C[(size_t)m * N + n] = v;
            } else {
                int h = n & 3, d = n >> 2;
                C[((size_t)h * M + m) * ATN_N + d] = v;
            }
        }
    }
}

// ----------------------- fused masked attention (flash-style) --------------
// Per block: one head, 32 query rows, loop over K/V in tiles of 32.
__global__ __launch_bounds__(256) void attn_kernel(
    const float* __restrict__ Qh, const float* __restrict__ Kh,
    const float* __restrict__ V, const int* __restrict__ batch_h,
    const int* __restrict__ batch_p, float* __restrict__ att)
{
    const int h = blockIdx.y;
    const int n0 = blockIdx.x * 32;
    const int t = threadIdx.x;

    __shared__ float Qs[32][132];
    __shared__ float Ks[32][132];
    __shared__ float Vs[32][192];
    __shared__ float Sl[32][33];
    __shared__ float Mrow[32], Lrow[32], Frow[32];
    __shared__ int bh[32], bm[32];

    const float* Qbase = Qh + ((size_t)h * NH_N + n0) * ATN_N;
#pragma unroll
    for (int l = 0; l < 16; l++) {
        int idx = t + l * 256;
        int r = idx >> 7, d = idx & 127;
        Qs[r][d] = Qbase[r * ATN_N + d];
    }
    if (t < 32) { bh[t] = batch_h[n0 + t]; Mrow[t] = -1e30f; Lrow[t] = 0.f; }

    const int rq = t >> 4;   // PV rows rq, rq+16
    const int cc = t & 15;   // PV dim chunk (12 dims)
    float acc0[12] = {}, acc1[12] = {};

    const int rS = t & 31;   // S-phase row
    const int mg = t >> 5;   // S-phase col group
    const float scale = 0.08838834764831845f;  // 1/sqrt(128)

    for (int m0 = 0; m0 < NP_N; m0 += 32) {
        __syncthreads();
        const float* Kbase = Kh + ((size_t)h * NP_N + m0) * ATN_N;
#pragma unroll
        for (int l = 0; l < 16; l++) {
            int idx = t + l * 256;
            int r = idx >> 7, d = idx & 127;
            Ks[r][d] = Kbase[r * ATN_N + d];
        }
        const float* Vbase = V + (size_t)m0 * BERT_N + h * VH_N;
#pragma unroll
        for (int l = 0; l < 6; l++) {
            int idx = t + l * 256;
            int mm = idx / 48, e4 = idx % 48;
            *(float4*)&Vs[mm][e4 * 4] = *(const float4*)&Vbase[(size_t)mm * BERT_N + e4 * 4];
        }
        if (t < 32) bm[t] = batch_p[m0 + t];
        __syncthreads();

        // --- scores ---
        {
            float s[4] = {};
#pragma unroll
            for (int d4 = 0; d4 < 32; d4++) {
                float4 q = *(const float4*)&Qs[rS][d4 * 4];
#pragma unroll
                for (int u = 0; u < 4; u++) {
                    float4 kk = *(const float4*)&Ks[mg + u * 8][d4 * 4];
                    s[u] += q.x * kk.x + q.y * kk.y + q.z * kk.z + q.w * kk.w;
                }
            }
            int bhr = bh[rS];
#pragma unroll
            for (int u = 0; u < 4; u++) {
                int mm = mg + u * 8;
                Sl[rS][mm] = (bhr == bm[mm]) ? -1e10f : s[u] * scale;
            }
        }
        __syncthreads();

        // --- online softmax stats (8 lanes per row, contiguous in wave) ---
        {
            int r = t >> 3, j = t & 7;
            float v[4];
            float mx = -1e30f;
#pragma unroll
            for (int u = 0; u < 4; u++) { v[u] = Sl[r][j + u * 8]; mx = fmaxf(mx, v[u]); }
#pragma unroll
            for (int off = 1; off < 8; off <<= 1) mx = fmaxf(mx, __shfl_xor(mx, off));
            float mold = Mrow[r];
            float mnew = fmaxf(mold, mx);
            float sum = 0.f;
#pragma unroll
            for (int u = 0; u < 4; u++) {
                float p = __expf(v[u] - mnew);
                Sl[r][j + u * 8] = p;
                sum += p;
            }
#pragma unroll
            for (int off = 1; off < 8; off <<= 1) sum += __shfl_xor(sum, off);
            if (j == 0) {
                float f = __expf(mold - mnew);
                Frow[r] = f;
                Lrow[r] = Lrow[r] * f + sum;
                Mrow[r] = mnew;
            }
        }
        __syncthreads();

        // --- PV accumulate ---
        {
            float f0 = Frow[rq], f1 = Frow[rq + 16];
#pragma unroll
            for (int e = 0; e < 12; e++) { acc0[e] *= f0; acc1[e] *= f1; }
#pragma unroll
            for (int mm = 0; mm < 32; mm++) {
                float p0 = Sl[rq][mm], p1 = Sl[rq + 16][mm];
#pragma unroll
                for (int e4 = 0; e4 < 3; e4++) {
                    float4 vv = *(const float4*)&Vs[mm][cc * 12 + e4 * 4];
                    acc0[e4 * 4 + 0] += p0 * vv.x; acc0[e4 * 4 + 1] += p0 * vv.y;
                    acc0[e4 * 4 + 2] += p0 * vv.z; acc0[e4 * 4 + 3] += p0 * vv.w;
                    acc1[e4 * 4 + 0] += p1 * vv.x; acc1[e4 * 4 + 1] += p1 * vv.y;
                    acc1[e4 * 4 + 2] += p1 * vv.z; acc1[e4 * 4 + 3] += p1 * vv.w;
                }
            }
        }
    }
    __syncthreads();
    float l0 = 1.f / Lrow[rq], l1 = 1.f / Lrow[rq + 16];
    float* o0 = att + (size_t)(n0 + rq) * BERT_N + h * VH_N + cc * 12;
    float* o1 = att + (size_t)(n0 + rq + 16) * BERT_N + h * VH_N + cc * 12;
#pragma unroll
    for (int e = 0; e < 12; e++) { o0[e] = acc0[e] * l0; o1[e] = acc1[e] * l1; }
}

// ----------------------- MLP (gelu) + Linear + LayerNorm -------------------
// 8 nodes per block.
__global__ __launch_bounds__(256) void mlp_kernel(
    const float* __restrict__ ctx_h, const float* __restrict__ lhs_h,
    const float* __restrict__ att, const float* __restrict__ W1,
    const float* __restrict__ b1, const float* __restrict__ W2,
    const float* __restrict__ ln_g, const float* __restrict__ ln_b,
    float* __restrict__ h2out)
{
    const int n0 = blockIdx.x * 8;
    const int t = threadIdx.x;
    __shared__ float fs[8][1280];
    __shared__ float h1s[8][256];
    __shared__ float h2s[8][128];

    // load feats = [ctx_h | lhs_h - attended]
#pragma unroll
    for (int l = 0; l < 10; l++) {
        int idx = t + l * 256;
        int i = idx / 320, c4 = idx % 320;
        int n = n0 + i;
        float4 v;
        if (c4 < 128) {
            v = *(const float4*)&ctx_h[(size_t)n * D_N + c4 * 4];
        } else {
            int j4 = c4 - 128;
            float4 a = *(const float4*)&lhs_h[(size_t)n * BERT_N + j4 * 4];
            float4 b = *(const float4*)&att[(size_t)n * BERT_N + j4 * 4];
            v = make_float4(a.x - b.x, a.y - b.y, a.z - b.z, a.w - b.w);
        }
        *(float4*)&fs[i][c4 * 4] = v;
    }
    __syncthreads();

    // h1 = gelu(feats @ W1 + b1); thread t owns output dim t for 8 nodes
    {
        float acc[8] = {};
        for (int i4 = 0; i4 < 320; i4++) {
            float w0 = W1[(size_t)(i4 * 4 + 0) * 256 + t];
            float w1 = W1[(size_t)(i4 * 4 + 1) * 256 + t];
            float w2 = W1[(size_t)(i4 * 4 + 2) * 256 + t];
            float w3 = W1[(size_t)(i4 * 4 + 3) * 256 + t];
#pragma unroll
            for (int nd = 0; nd < 8; nd++) {
                float4 f = *(const float4*)&fs[nd][i4 * 4];
                acc[nd] += f.x * w0 + f.y * w1 + f.z * w2 + f.w * w3;
            }
        }
        float bb = b1[t];
#pragma unroll
        for (int nd = 0; nd < 8; nd++) {
            float x = acc[nd] + bb;
            h1s[nd][t] = 0.5f * x * (1.f + erff(x * 0.70710678118654752f));
        }
    }
    __syncthreads();

    // h2 = h1 @ W2 (no bias); thread -> (dim o2, 4 nodes)
    {
        int o2 = t & 127, g = t >> 7;
        float acc[4] = {};
        for (int k4 = 0; k4 < 64; k4++) {
            float w0 = W2[(size_t)(k4 * 4 + 0) * 128 + o2];
            float w1 = W2[(size_t)(k4 * 4 + 1) * 128 + o2];
            float w2 = W2[(size_t)(k4 * 4 + 2) * 128 + o2];
            float w3 = W2[(size_t)(k4 * 4 + 3) * 128 + o2];
#pragma unroll
            for (int q = 0; q < 4; q++) {
                float4 hh = *(const float4*)&h1s[g * 4 + q][k4 * 4];
                acc[q] += hh.x * w0 + hh.y * w1 + hh.z * w2 + hh.w * w3;
            }
        }
#pragma unroll
        for (int q = 0; q < 4; q++) h2s[g * 4 + q][o2] = acc[q];
    }
    __syncthreads();

    // LayerNorm(128), two-pass; wave w handles nodes 2w, 2w+1
    {
        int wv = t >> 6, lane = t & 63;
#pragma unroll
        for (int s = 0; s < 2; s++) {
            int nd = wv * 2 + s;
            float x0 = h2s[nd][lane], x1 = h2s[nd][lane + 64];
            float sum = x0 + x1;
#pragma unroll
            for (int off = 32; off; off >>= 1) sum += __shfl_xor(sum, off);
            float mu = sum * (1.f / 128.f);
            float d0 = x0 - mu, d1 = x1 - mu;
            float s2 = d0 * d0 + d1 * d1;
#pragma unroll
            for (int off = 32; off; off >>= 1) s2 += __shfl_xor(s2, off);
            float rstd = rsqrtf(s2 * (1.f / 128.f) + 1e-5f);
            size_t base = (size_t)(n0 + nd) * 128;
            h2out[base + lane]      = d0 * rstd * ln_g[lane] + ln_b[lane];
            h2out[base + lane + 64] = d1 * rstd * ln_g[lane + 64] + ln_b[lane + 64];
        }
    }
}

// ----------------------- segment ranges (batch ids are sorted) -------------
__global__ void ranges_kernel(const int* __restrict__ bh, int* __restrict__ lo,
                              int Nn, int Bn)
{
    int n = blockIdx.x * blockDim.x + threadIdx.x;
    if (n >= Nn) return;
    int b = bh[n];
    int prev = (n == 0) ? -1 : bh[n - 1];
    for (int bb = prev + 1; bb <= b; bb++) lo[bb] = n;
    if (n == Nn - 1) for (int bb = b + 1; bb <= Bn; bb++) lo[bb] = Nn;
}

// ----------------------- pool (mean per graph) + classifier ----------------
__global__ __launch_bounds__(128) void pool_cls(
    const float* __restrict__ h2, const int* __restrict__ lo,
    const float* __restrict__ Wc, const float* __restrict__ bc,
    float* __restrict__ out)
{
    int b = blockIdx.x, t = threadIdx.x;
    int s = lo[b], e = lo[b + 1];
    float acc = 0.f;
    for (int n = s; n < e; n++) acc += h2[(size_t)n * 128 + t];
    float pooled = acc / fmaxf((float)(e - s), 1.f);
    __shared__ float red[128];
    for (int c = 0; c < 3; c++) {
        red[t] = pooled * Wc[t * 3 + c];
        __syncthreads();
        for (int off = 64; off > 0; off >>= 1) {
            if (t < off) red[t] += red[t + off];
            __syncthreads();
        }
        if (t == 0) out[b * 3 + c] = red[0] + bc[c];
        __syncthreads();
    }
}

// ---------------------------------------------------------------------------
extern "C" void kernel_launch(void* const* d_in, const int* in_sizes, int n_in,
                              void* d_out, int out_size, void* d_ws, size_t ws_size,
                              hipStream_t stream)
{
    const float* ctx_p  = (const float*)d_in[0];
    const float* ctx_h  = (const float*)d_in[1];
    const float* lhs_p  = (const float*)d_in[2];
    const float* lhs_h  = (const float*)d_in[3];
    const int*   batch_p = (const int*)d_in[4];
    const int*   batch_h = (const int*)d_in[5];
    const float* Wq = (const float*)d_in[6];
    const float* bq = (const float*)d_in[7];
    const float* Wk = (const float*)d_in[8];
    const float* bk = (const float*)d_in[9];
    const float* Wv = (const float*)d_in[10];
    const float* bv = (const float*)d_in[11];
    const float* W1 = (const float*)d_in[12];
    const float* b1 = (const float*)d_in[13];
    const float* W2 = (const float*)d_in[14];
    const float* ln_g = (const float*)d_in[15];
    const float* ln_b = (const float*)d_in[16];
    const float* Wc = (const float*)d_in[17];
    const float* bc = (const float*)d_in[18];
    float* out = (float*)d_out;

    float* ws  = (float*)d_ws;
    float* Qh  = ws;                                   // 4*4096*128
    float* Kh  = Qh + (size_t)H_N * NH_N * ATN_N;      // 4*4096*128
    float* Vb  = Kh + (size_t)H_N * NP_N * ATN_N;      // 4096*768
    float* att = Vb + (size_t)NP_N * BERT_N;           // 4096*768
    float* h2  = att + (size_t)NH_N * BERT_N;          // 4096*128
    int*   lo  = (int*)(h2 + (size_t)NH_N * 128);      // 33 ints

    gemm_bias<<<dim3(8, 64), 256, 0, stream>>>(ctx_h, Wq, bq, Qh, NH_N, D_N, D_N, 1);
    gemm_bias<<<dim3(8, 64), 256, 0, stream>>>(ctx_p, Wk, bk, Kh, NP_N, D_N, D_N, 1);
    gemm_bias<<<dim3(12, 64), 256, 0, stream>>>(lhs_p, Wv, bv, Vb, NP_N, BERT_N, BERT_N, 0);
    attn_kernel<<<dim3(NH_N / 32, H_N), 256, 0, stream>>>(Qh, Kh, Vb, batch_h, batch_p, att);
    mlp_kernel<<<NH_N / 8, 256, 0, stream>>>(ctx_h, lhs_h, att, W1, b1, W2, ln_g, ln_b, h2);
    ranges_kernel<<<16, 256, 0, stream>>>(batch_h, lo, NH_N, B_N);
    pool_cls<<<B_N, 128, 0, stream>>>(h2, lo, Wc, bc, out);
}

// Round 2
// 431.203 us; speedup vs baseline: 2.7395x; 2.7395x over previous
//
#include <hip/hip_runtime.h>
#include <hip/hip_bf16.h>
#include <math.h>

#define NP_N 4096
#define NH_N 4096
#define D_N 512
#define BERT_N 768
#define H_N 4
#define ATN_N 128
#define VH_N 192
#define B_N 32
#define KB 64
#define QB 64

typedef __attribute__((ext_vector_type(8))) short short8;
typedef __attribute__((ext_vector_type(4))) float f32x4;

__device__ __forceinline__ void gl_lds16(const void* g, void* l) {
    __builtin_amdgcn_global_load_lds((const __attribute__((address_space(1))) void*)g,
                                     (__attribute__((address_space(3))) void*)l, 16, 0, 0);
}
__device__ __forceinline__ void gl_lds4(const void* g, void* l) {
    __builtin_amdgcn_global_load_lds((const __attribute__((address_space(1))) void*)g,
                                     (__attribute__((address_space(3))) void*)l, 4, 0, 0);
}
__device__ __forceinline__ unsigned int pkbf(float a, float b) {
    union { __hip_bfloat162 h; unsigned int u; } x;
    x.h.x = __float2bfloat16(a);
    x.h.y = __float2bfloat16(b);
    return x.u;
}

// ----------------------- tiled f32 GEMM + bias, bf16 stores ----------------
// MODE 1: head-deinterleave for Q/K: col n -> (h=n&3, d=n>>2), C=[H][M][128] bf16
// MODE 2: V transposed per head: col n -> (h=n/192, vd=n%192), C=[H][192][M] bf16
template<int MODE>
__global__ __launch_bounds__(256) void gemm_bias_b(
    const float* __restrict__ A, const float* __restrict__ W,
    const float* __restrict__ bias, __hip_bfloat16* __restrict__ C,
    int M, int N, int K)
{
    __shared__ float As[64][20];
    __shared__ float Ws[16][64];
    const int t = threadIdx.x;
    const int tx = t & 15, ty = t >> 4;
    const int m0 = blockIdx.y * 64, n0 = blockIdx.x * 64;

    float c[4][4] = {};
    for (int k0 = 0; k0 < K; k0 += 16) {
        __syncthreads();
#pragma unroll
        for (int l = 0; l < 4; l++) {
            int idx = t + l * 256;
            int m = idx >> 4, kk = idx & 15;
            As[m][kk] = A[(size_t)(m0 + m) * K + k0 + kk];
        }
#pragma unroll
        for (int l = 0; l < 4; l++) {
            int idx = t + l * 256;
            int kk = idx >> 6, n = idx & 63;
            Ws[kk][n] = W[(size_t)(k0 + kk) * N + n0 + n];
        }
        __syncthreads();
#pragma unroll
        for (int k4 = 0; k4 < 4; k4++) {
            float4 a4[4], w4[4];
#pragma unroll
            for (int i = 0; i < 4; i++) a4[i] = *(const float4*)&As[ty * 4 + i][k4 * 4];
#pragma unroll
            for (int kk = 0; kk < 4; kk++) w4[kk] = *(const float4*)&Ws[k4 * 4 + kk][tx * 4];
#pragma unroll
            for (int i = 0; i < 4; i++) {
                const float a0 = a4[i].x, a1 = a4[i].y, a2 = a4[i].z, a3 = a4[i].w;
                c[i][0] += a0 * w4[0].x + a1 * w4[1].x + a2 * w4[2].x + a3 * w4[3].x;
                c[i][1] += a0 * w4[0].y + a1 * w4[1].y + a2 * w4[2].y + a3 * w4[3].y;
                c[i][2] += a0 * w4[0].z + a1 * w4[1].z + a2 * w4[2].z + a3 * w4[3].z;
                c[i][3] += a0 * w4[0].w + a1 * w4[1].w + a2 * w4[2].w + a3 * w4[3].w;
            }
        }
    }
#pragma unroll
    for (int i = 0; i < 4; i++) {
        int m = m0 + ty * 4 + i;
#pragma unroll
        for (int j = 0; j < 4; j++) {
            int n = n0 + tx * 4 + j;
            float v = c[i][j] + bias[n];
            if (MODE == 1) {
                int h = n & 3, d = n >> 2;
                C[((size_t)h * M + m) * 128 + d] = __float2bfloat16(v);
            } else {
                int h = n / 192, vd = n - h * 192;
                C[((size_t)(h * 192 + vd)) * M + m] = __float2bfloat16(v);
            }
        }
    }
}

// ----------------------- MFMA bf16 flash attention -------------------------
// block: 1 head x 64 queries, 4 waves (wave = 16 queries).
// S^T = K·Q^T  (16x16x32 MFMA, A=K frag from LDS, B=Q frag in regs)
// online softmax over columns; P staged per-wave in LDS; O = P·V (V^T in LDS).
__global__ __launch_bounds__(256) void attn_mfma(
    const __hip_bfloat16* __restrict__ Qb,   // [4][4096][128]
    const __hip_bfloat16* __restrict__ Kb,   // [4][4096][128]
    const __hip_bfloat16* __restrict__ Vtb,  // [4][192][4096]
    const int* __restrict__ batch_h, const int* __restrict__ batch_p,
    float* __restrict__ att)
{
    // XCD-aware decode: 2 XCDs per head -> per-XCD L2 holds one head's K/V
    const int bid = blockIdx.x;
    const int xcd = bid & 7;
    const int h = xcd >> 1;
    const int qblk = (xcd & 1) * 32 + (bid >> 3);
    const int n0 = qblk * QB;

    __shared__ unsigned short Kt[2][KB * 128];
    __shared__ unsigned short Vt[2][192 * KB];
    __shared__ int bps[2][KB];
    __shared__ unsigned short Pl[4][16 * 72];

    const int t = threadIdx.x;
    const int w = t >> 6;
    const int lane = t & 63;
    const int lq = lane & 15;
    const int g = lane >> 4;
    const float scale = 0.08838834764831845f;  // 1/sqrt(128)

    // Q fragments, loop-invariant: rows n0+w*16+lq, k = ks*32+g*8..+7
    short8 qf[4];
    {
        const __hip_bfloat16* qrow = Qb + ((size_t)h * NH_N + n0 + w * 16 + lq) * 128;
#pragma unroll
        for (int ks = 0; ks < 4; ks++)
            qf[ks] = *(const short8*)(qrow + ks * 32 + g * 8);
    }
    const int bhq = batch_h[n0 + w * 16 + lq];

    f32x4 Ofr[12];
#pragma unroll
    for (int nt = 0; nt < 12; nt++) Ofr[nt] = (f32x4){0.f, 0.f, 0.f, 0.f};
    float m_run = -1e30f, l_run = 0.f;

    const char* Kg = (const char*)(Kb + (size_t)h * NP_N * 128);
    const char* Vg = (const char*)(Vtb + (size_t)h * 192 * (size_t)NP_N);

    auto STAGE = [&](int buf, int m0) {
        // K tile: 16 x 1KB instrs, this wave does 4
#pragma unroll
        for (int jj = 0; jj < 4; jj++) {
            int j = w * 4 + jj;
            int r = j * 4 + (lane >> 4);
            int c = (lane & 15) * 16;
            const char* src = Kg + (size_t)(m0 + r) * 256 + (c ^ ((r & 7) << 4));
            gl_lds16(src, (void*)&Kt[buf][j * 512]);
        }
        // V^T tile: 24 instrs, this wave does 6
#pragma unroll
        for (int jj = 0; jj < 6; jj++) {
            int j = w * 6 + jj;
            int r = j * 8 + (lane >> 3);
            int c = (lane & 7) * 16;
            const char* src = Vg + ((size_t)r * NP_N + m0) * 2 + (c ^ ((r & 7) << 4));
            gl_lds16(src, (void*)&Vt[buf][j * 512]);
        }
        if (w == 0) gl_lds4(batch_p + m0 + lane, (void*)&bps[buf][0]);
    };

    STAGE(0, 0);
    __syncthreads();
    int cur = 0;

    for (int tile = 0; tile < NP_N / KB; tile++) {
        if (tile + 1 < NP_N / KB) STAGE(cur ^ 1, (tile + 1) * KB);

        // ---- S^T = K·Q^T : 4 key-Mtiles x 4 k-steps ----
        f32x4 S[4];
#pragma unroll
        for (int mt = 0; mt < 4; mt++) S[mt] = (f32x4){0.f, 0.f, 0.f, 0.f};
        const char* Kbase = (const char*)&Kt[cur][0];
#pragma unroll
        for (int mt = 0; mt < 4; mt++) {
            int r = mt * 16 + lq;
            int swz = (lq & 7) << 4;
#pragma unroll
            for (int ks = 0; ks < 4; ks++) {
                short8 kf = *(const short8*)(Kbase + r * 256 + ((ks * 64 + g * 16) ^ swz));
                S[mt] = __builtin_amdgcn_mfma_f32_16x16x32_bf16(kf, qf[ks], S[mt], 0, 0, 0);
            }
        }

        // ---- mask + scale + online softmax (per column q = lq) ----
        int4 bp4[4];
#pragma unroll
        for (int mt = 0; mt < 4; mt++)
            bp4[mt] = *(const int4*)&bps[cur][16 * mt + 4 * g];

        float mx = -1e30f;
#pragma unroll
        for (int mt = 0; mt < 4; mt++) {
            float v0 = (bp4[mt].x == bhq) ? -1e10f : S[mt][0] * scale;
            float v1 = (bp4[mt].y == bhq) ? -1e10f : S[mt][1] * scale;
            float v2 = (bp4[mt].z == bhq) ? -1e10f : S[mt][2] * scale;
            float v3 = (bp4[mt].w == bhq) ? -1e10f : S[mt][3] * scale;
            S[mt][0] = v0; S[mt][1] = v1; S[mt][2] = v2; S[mt][3] = v3;
            mx = fmaxf(mx, fmaxf(fmaxf(v0, v1), fmaxf(v2, v3)));
        }
        mx = fmaxf(mx, __shfl_xor(mx, 16));
        mx = fmaxf(mx, __shfl_xor(mx, 32));

        float m_new = fmaxf(m_run, mx);
        float rsum = 0.f;
#pragma unroll
        for (int mt = 0; mt < 4; mt++) {
            float e0 = __expf(S[mt][0] - m_new);
            float e1 = __expf(S[mt][1] - m_new);
            float e2 = __expf(S[mt][2] - m_new);
            float e3 = __expf(S[mt][3] - m_new);
            S[mt][0] = e0; S[mt][1] = e1; S[mt][2] = e2; S[mt][3] = e3;
            rsum += (e0 + e1) + (e2 + e3);
            uint2 pw;
            pw.x = pkbf(e0, e1);
            pw.y = pkbf(e2, e3);
            *(uint2*)((char*)&Pl[w][0] + lq * 144 + mt * 32 + g * 8) = pw;
        }
        rsum += __shfl_xor(rsum, 16);
        rsum += __shfl_xor(rsum, 32);

        if (__all(mx <= m_run)) {
            l_run += rsum;
        } else {
            float f = __expf(m_run - m_new);
            l_run = l_run * f + rsum;
            m_run = m_new;
            float fr0 = __shfl(f, 4 * g + 0);
            float fr1 = __shfl(f, 4 * g + 1);
            float fr2 = __shfl(f, 4 * g + 2);
            float fr3 = __shfl(f, 4 * g + 3);
#pragma unroll
            for (int nt = 0; nt < 12; nt++) {
                Ofr[nt][0] *= fr0; Ofr[nt][1] *= fr1;
                Ofr[nt][2] *= fr2; Ofr[nt][3] *= fr3;
            }
        }

        // ---- O += P·V  (A = P from wave-private LDS, B = V^T tile) ----
        const char* Vbase = (const char*)&Vt[cur][0];
#pragma unroll
        for (int ks = 0; ks < 2; ks++) {
            short8 pf = *(const short8*)((const char*)&Pl[w][0] + lq * 144 + ks * 64 + g * 16);
            int swz = (lq & 7) << 4;
#pragma unroll
            for (int nt = 0; nt < 12; nt++) {
                int vd = nt * 16 + lq;
                short8 vf = *(const short8*)(Vbase + vd * 128 + ((ks * 64 + g * 16) ^ swz));
                Ofr[nt] = __builtin_amdgcn_mfma_f32_16x16x32_bf16(pf, vf, Ofr[nt], 0, 0, 0);
            }
        }

        __syncthreads();
        cur ^= 1;
    }

    // ---- epilogue: normalize by l, store ----
    float lr0 = __shfl(l_run, 4 * g + 0);
    float lr1 = __shfl(l_run, 4 * g + 1);
    float lr2 = __shfl(l_run, 4 * g + 2);
    float lr3 = __shfl(l_run, 4 * g + 3);
    float i0 = 1.f / lr0, i1 = 1.f / lr1, i2 = 1.f / lr2, i3 = 1.f / lr3;
#pragma unroll
    for (int nt = 0; nt < 12; nt++) {
        int col = h * 192 + nt * 16 + lq;
        size_t r0 = (size_t)(n0 + w * 16 + 4 * g) * BERT_N + col;
        att[r0] = Ofr[nt][0] * i0;
        att[r0 + BERT_N] = Ofr[nt][1] * i1;
        att[r0 + 2 * BERT_N] = Ofr[nt][2] * i2;
        att[r0 + 3 * BERT_N] = Ofr[nt][3] * i3;
    }
}

// ----------------------- MLP (gelu) + Linear + LayerNorm -------------------
__global__ __launch_bounds__(256) void mlp_kernel(
    const float* __restrict__ ctx_h, const float* __restrict__ lhs_h,
    const float* __restrict__ att, const float* __restrict__ W1,
    const float* __restrict__ b1, const float* __restrict__ W2,
    const float* __restrict__ ln_g, const float* __restrict__ ln_b,
    float* __restrict__ h2out)
{
    const int n0 = blockIdx.x * 8;
    const int t = threadIdx.x;
    __shared__ float fs[8][1280];
    __shared__ float h1s[8][256];
    __shared__ float h2s[8][128];

#pragma unroll
    for (int l = 0; l < 10; l++) {
        int idx = t + l * 256;
        int i = idx / 320, c4 = idx % 320;
        int n = n0 + i;
        float4 v;
        if (c4 < 128) {
            v = *(const float4*)&ctx_h[(size_t)n * D_N + c4 * 4];
        } else {
            int j4 = c4 - 128;
            float4 a = *(const float4*)&lhs_h[(size_t)n * BERT_N + j4 * 4];
            float4 b = *(const float4*)&att[(size_t)n * BERT_N + j4 * 4];
            v = make_float4(a.x - b.x, a.y - b.y, a.z - b.z, a.w - b.w);
        }
        *(float4*)&fs[i][c4 * 4] = v;
    }
    __syncthreads();

    {
        float acc[8] = {};
        for (int i4 = 0; i4 < 320; i4++) {
            float w0 = W1[(size_t)(i4 * 4 + 0) * 256 + t];
            float w1 = W1[(size_t)(i4 * 4 + 1) * 256 + t];
            float w2 = W1[(size_t)(i4 * 4 + 2) * 256 + t];
            float w3 = W1[(size_t)(i4 * 4 + 3) * 256 + t];
#pragma unroll
            for (int nd = 0; nd < 8; nd++) {
                float4 f = *(const float4*)&fs[nd][i4 * 4];
                acc[nd] += f.x * w0 + f.y * w1 + f.z * w2 + f.w * w3;
            }
        }
        float bb = b1[t];
#pragma unroll
        for (int nd = 0; nd < 8; nd++) {
            float x = acc[nd] + bb;
            h1s[nd][t] = 0.5f * x * (1.f + erff(x * 0.70710678118654752f));
        }
    }
    __syncthreads();

    {
        int o2 = t & 127, gq = t >> 7;
        float acc[4] = {};
        for (int k4 = 0; k4 < 64; k4++) {
            float w0 = W2[(size_t)(k4 * 4 + 0) * 128 + o2];
            float w1 = W2[(size_t)(k4 * 4 + 1) * 128 + o2];
            float w2 = W2[(size_t)(k4 * 4 + 2) * 128 + o2];
            float w3 = W2[(size_t)(k4 * 4 + 3) * 128 + o2];
#pragma unroll
            for (int q = 0; q < 4; q++) {
                float4 hh = *(const float4*)&h1s[gq * 4 + q][k4 * 4];
                acc[q] += hh.x * w0 + hh.y * w1 + hh.z * w2 + hh.w * w3;
            }
        }
#pragma unroll
        for (int q = 0; q < 4; q++) h2s[gq * 4 + q][o2] = acc[q];
    }
    __syncthreads();

    {
        int wv = t >> 6, lane = t & 63;
#pragma unroll
        for (int s = 0; s < 2; s++) {
            int nd = wv * 2 + s;
            float x0 = h2s[nd][lane], x1 = h2s[nd][lane + 64];
            float sum = x0 + x1;
#pragma unroll
            for (int off = 32; off; off >>= 1) sum += __shfl_xor(sum, off);
            float mu = sum * (1.f / 128.f);
            float d0 = x0 - mu, d1 = x1 - mu;
            float s2 = d0 * d0 + d1 * d1;
#pragma unroll
            for (int off = 32; off; off >>= 1) s2 += __shfl_xor(s2, off);
            float rstd = rsqrtf(s2 * (1.f / 128.f) + 1e-5f);
            size_t base = (size_t)(n0 + nd) * 128;
            h2out[base + lane]      = d0 * rstd * ln_g[lane] + ln_b[lane];
            h2out[base + lane + 64] = d1 * rstd * ln_g[lane + 64] + ln_b[lane + 64];
        }
    }
}

// ----------------------- segment ranges (batch ids sorted) -----------------
__global__ void ranges_kernel(const int* __restrict__ bh, int* __restrict__ lo,
                              int Nn, int Bn)
{
    int n = blockIdx.x * blockDim.x + threadIdx.x;
    if (n >= Nn) return;
    int b = bh[n];
    int prev = (n == 0) ? -1 : bh[n - 1];
    for (int bb = prev + 1; bb <= b; bb++) lo[bb] = n;
    if (n == Nn - 1) for (int bb = b + 1; bb <= Bn; bb++) lo[bb] = Nn;
}

// ----------------------- pool (mean per graph) + classifier ----------------
__global__ __launch_bounds__(128) void pool_cls(
    const float* __restrict__ h2, const int* __restrict__ lo,
    const float* __restrict__ Wc, const float* __restrict__ bc,
    float* __restrict__ out)
{
    int b = blockIdx.x, t = threadIdx.x;
    int s = lo[b], e = lo[b + 1];
    float acc = 0.f;
    for (int n = s; n < e; n++) acc += h2[(size_t)n * 128 + t];
    float pooled = acc / fmaxf((float)(e - s), 1.f);
    __shared__ float red[128];
    for (int c = 0; c < 3; c++) {
        red[t] = pooled * Wc[t * 3 + c];
        __syncthreads();
        for (int off = 64; off > 0; off >>= 1) {
            if (t < off) red[t] += red[t + off];
            __syncthreads();
        }
        if (t == 0) out[b * 3 + c] = red[0] + bc[c];
        __syncthreads();
    }
}

// ---------------------------------------------------------------------------
extern "C" void kernel_launch(void* const* d_in, const int* in_sizes, int n_in,
                              void* d_out, int out_size, void* d_ws, size_t ws_size,
                              hipStream_t stream)
{
    const float* ctx_p  = (const float*)d_in[0];
    const float* ctx_h  = (const float*)d_in[1];
    const float* lhs_p  = (const float*)d_in[2];
    const float* lhs_h  = (const float*)d_in[3];
    const int*   batch_p = (const int*)d_in[4];
    const int*   batch_h = (const int*)d_in[5];
    const float* Wq = (const float*)d_in[6];
    const float* bq = (const float*)d_in[7];
    const float* Wk = (const float*)d_in[8];
    const float* bk = (const float*)d_in[9];
    const float* Wv = (const float*)d_in[10];
    const float* bv = (const float*)d_in[11];
    const float* W1 = (const float*)d_in[12];
    const float* b1 = (const float*)d_in[13];
    const float* W2 = (const float*)d_in[14];
    const float* ln_g = (const float*)d_in[15];
    const float* ln_b = (const float*)d_in[16];
    const float* Wc = (const float*)d_in[17];
    const float* bc = (const float*)d_in[18];
    float* out = (float*)d_out;

    __hip_bfloat16* Qb  = (__hip_bfloat16*)d_ws;                     // 4*4096*128
    __hip_bfloat16* Kb  = Qb + (size_t)H_N * NH_N * 128;             // 4*4096*128
    __hip_bfloat16* Vtb = Kb + (size_t)H_N * NP_N * 128;             // 4*192*4096
    float* att = (float*)(Vtb + (size_t)H_N * 192 * NP_N);           // 4096*768
    float* h2  = att + (size_t)NH_N * BERT_N;                        // 4096*128
    int*   lo  = (int*)(h2 + (size_t)NH_N * 128);                    // 33 ints

    gemm_bias_b<1><<<dim3(8, 64), 256, 0, stream>>>(ctx_h, Wq, bq, Qb, NH_N, D_N, D_N);
    gemm_bias_b<1><<<dim3(8, 64), 256, 0, stream>>>(ctx_p, Wk, bk, Kb, NP_N, D_N, D_N);
    gemm_bias_b<2><<<dim3(12, 64), 256, 0, stream>>>(lhs_p, Wv, bv, Vtb, NP_N, BERT_N, BERT_N);
    attn_mfma<<<256, 256, 0, stream>>>(Qb, Kb, Vtb, batch_h, batch_p, att);
    mlp_kernel<<<NH_N / 8, 256, 0, stream>>>(ctx_h, lhs_h, att, W1, b1, W2, ln_g, ln_b, h2);
    ranges_kernel<<<16, 256, 0, stream>>>(batch_h, lo, NH_N, B_N);
    pool_cls<<<B_N, 128, 0, stream>>>(h2, lo, Wc, bc, out);
}

// Round 3
// 194.432 us; speedup vs baseline: 6.0754x; 2.2178x over previous
//
#include <hip/hip_runtime.h>
#include <hip/hip_bf16.h>
#include <math.h>

#define NP_N 4096
#define NH_N 4096
#define D_N 512
#define BERT_N 768
#define H_N 4
#define B_N 32

typedef __attribute__((ext_vector_type(8))) short short8;
typedef __attribute__((ext_vector_type(4))) float f32x4;
typedef __attribute__((ext_vector_type(4))) unsigned short ush4;
typedef unsigned short ushort_t;

__device__ __forceinline__ void gl_lds16(const void* g, void* l) {
    __builtin_amdgcn_global_load_lds((const __attribute__((address_space(1))) void*)g,
                                     (__attribute__((address_space(3))) void*)l, 16, 0, 0);
}
__device__ __forceinline__ void gl_lds4(const void* g, void* l) {
    __builtin_amdgcn_global_load_lds((const __attribute__((address_space(1))) void*)g,
                                     (__attribute__((address_space(3))) void*)l, 4, 0, 0);
}
__device__ __forceinline__ unsigned short f2bu(float f) {
    __hip_bfloat16 b = __float2bfloat16(f);
    return *reinterpret_cast<unsigned short*>(&b);
}
__device__ __forceinline__ float b2f(unsigned short u) {
    union { unsigned int i; float f; } x; x.i = ((unsigned int)u) << 16; return x.f;
}
__device__ __forceinline__ unsigned int pkbf(float a, float b) {
    union { __hip_bfloat162 h; unsigned int u; } x;
    x.h.x = __float2bfloat16(a);
    x.h.y = __float2bfloat16(b);
    return x.u;
}

// =========================== convert + transpose ===========================
// blocks [0,512): elementwise f32->bf16 (ctx_h -> ctxh_bf + feats[:, :512],
//                 ctx_p -> ctxp_bf, lhs_p -> lhsp_bf), block 0 also permutes biases
// blocks [512,864): 64x64 weight transposes (Wq,Wk perm; Wv; W1)
#define EW_BLOCKS 512
__global__ __launch_bounds__(256) void convert_all(
    const float* __restrict__ ctx_h, const float* __restrict__ ctx_p,
    const float* __restrict__ lhs_p,
    const float* __restrict__ Wq, const float* __restrict__ Wk,
    const float* __restrict__ Wv, const float* __restrict__ W1,
    const float* __restrict__ bq, const float* __restrict__ bk,
    ushort_t* __restrict__ ctxh_bf, ushort_t* __restrict__ ctxp_bf,
    ushort_t* __restrict__ lhsp_bf, ushort_t* __restrict__ feats,
    ushort_t* __restrict__ Wqt, ushort_t* __restrict__ Wkt,
    ushort_t* __restrict__ Wvt, ushort_t* __restrict__ W1t,
    float* __restrict__ bqp, float* __restrict__ bkp)
{
    const int bid = blockIdx.x, t = threadIdx.x;
    if (bid < EW_BLOCKS) {
        const long N0 = 524288, N1 = 1048576, TOT = 1835008;
        for (long i = (long)bid * 256 + t; i < TOT; i += (long)EW_BLOCKS * 256) {
            const float4* src; ush4* dst; long k;
            if (i < N0)      { src = (const float4*)ctx_h; dst = (ush4*)ctxh_bf; k = i; }
            else if (i < N1) { src = (const float4*)ctx_p; dst = (ush4*)ctxp_bf; k = i - N0; }
            else             { src = (const float4*)lhs_p; dst = (ush4*)lhsp_bf; k = i - N1; }
            float4 v = src[k];
            ush4 o; o[0] = f2bu(v.x); o[1] = f2bu(v.y); o[2] = f2bu(v.z); o[3] = f2bu(v.w);
            dst[k] = o;
            if (i < N0) {
                long n = k >> 7, c4 = k & 127;   // 128 ush4 groups per 512-col row
                ((ush4*)feats)[n * 320 + c4] = o;
            }
        }
        if (bid == 0) {
            for (int n = t; n < 512; n += 256) {
                int np = (n & 3) * 128 + (n >> 2);
                bqp[np] = bq[n];
                bkp[np] = bk[n];
            }
        }
        return;
    }
    // transposes
    int tb = bid - EW_BLOCKS;
    const float* src; ushort_t* dst; int K, N, tile, perm;
    if (tb < 64)       { src = Wq; dst = Wqt; K = 512;  N = 512; tile = tb;       perm = 1; }
    else if (tb < 128) { src = Wk; dst = Wkt; K = 512;  N = 512; tile = tb - 64;  perm = 1; }
    else if (tb < 272) { src = Wv; dst = Wvt; K = 768;  N = 768; tile = tb - 128; perm = 0; }
    else               { src = W1; dst = W1t; K = 1280; N = 256; tile = tb - 272; perm = 0; }
    int ntn = N >> 6;
    int k0 = (tile / ntn) * 64, n0 = (tile % ntn) * 64;
    __shared__ float tl[64][65];
#pragma unroll
    for (int i = 0; i < 16; i++) {
        int idx = t + i * 256; int r = idx >> 6, c = idx & 63;
        tl[r][c] = src[(size_t)(k0 + r) * N + n0 + c];
    }
    __syncthreads();
#pragma unroll
    for (int i = 0; i < 16; i++) {
        int idx = t + i * 256; int r = idx >> 6, c = idx & 63;
        int n = n0 + r;
        int nr = perm ? ((n & 3) * 128 + (n >> 2)) : n;
        dst[(size_t)nr * K + k0 + c] = f2bu(tl[c][r]);
    }
}

// =========================== bf16 MFMA GEMM =================================
// C[m][n] = sum_k A[m][k] * Bt[n][k]  (+bias, optional GELU), bf16 out.
// 64x64 tile, BK=64, 4 waves in 2x2 grid (each wave 32x32).
template<int BIAS_ROW, int GELU>
__global__ __launch_bounds__(256) void gemm_bf(
    const ushort_t* __restrict__ A, const ushort_t* __restrict__ Bt,
    const float* __restrict__ bias, ushort_t* __restrict__ C,
    int M, int N, int K)
{
    __shared__ ushort_t As[2][64 * 64];
    __shared__ ushort_t Bs[2][64 * 64];
    const int t = threadIdx.x, w = t >> 6, lane = t & 63;
    const int lq = lane & 15, g = lane >> 4;
    const int wm = w >> 1, wn = w & 1;
    const int n0 = blockIdx.x * 64, m0 = blockIdx.y * 64;
    const int nsteps = K >> 6;

    f32x4 acc[2][2];
#pragma unroll
    for (int a = 0; a < 2; a++)
#pragma unroll
        for (int b = 0; b < 2; b++) acc[a][b] = (f32x4){0.f, 0.f, 0.f, 0.f};

    auto STAGE = [&](int buf, int k0) {
#pragma unroll
        for (int jj = 0; jj < 2; jj++) {
            int j = w * 2 + jj;
            int r = j * 8 + (lane >> 3);
            int c = (lane & 7) * 16;
            int cs = c ^ ((r & 7) << 4);
            gl_lds16((const char*)A + ((size_t)(m0 + r) * K + k0) * 2 + cs, (void*)&As[buf][j * 512]);
            gl_lds16((const char*)Bt + ((size_t)(n0 + r) * K + k0) * 2 + cs, (void*)&Bs[buf][j * 512]);
        }
    };

    STAGE(0, 0);
    __syncthreads();
    int cur = 0;
    for (int s = 0; s < nsteps; s++) {
        if (s + 1 < nsteps) STAGE(cur ^ 1, (s + 1) * 64);
        const char* Ab = (const char*)&As[cur][0];
        const char* Bb = (const char*)&Bs[cur][0];
        const int swz = (lq & 7) << 4;
        short8 af[2][2], bf[2][2];
#pragma unroll
        for (int mf = 0; mf < 2; mf++) {
            int r = wm * 32 + mf * 16 + lq;
#pragma unroll
            for (int ks = 0; ks < 2; ks++)
                af[mf][ks] = *(const short8*)(Ab + r * 128 + ((ks * 64 + g * 16) ^ swz));
        }
#pragma unroll
        for (int nf = 0; nf < 2; nf++) {
            int r = wn * 32 + nf * 16 + lq;
#pragma unroll
            for (int ks = 0; ks < 2; ks++)
                bf[nf][ks] = *(const short8*)(Bb + r * 128 + ((ks * 64 + g * 16) ^ swz));
        }
#pragma unroll
        for (int mf = 0; mf < 2; mf++)
#pragma unroll
            for (int nf = 0; nf < 2; nf++)
#pragma unroll
                for (int ks = 0; ks < 2; ks++)
                    acc[mf][nf] = __builtin_amdgcn_mfma_f32_16x16x32_bf16(
                        af[mf][ks], bf[nf][ks], acc[mf][nf], 0, 0, 0);
        __syncthreads();
        cur ^= 1;
    }

#pragma unroll
    for (int mf = 0; mf < 2; mf++) {
#pragma unroll
        for (int nf = 0; nf < 2; nf++) {
            int ncol = n0 + wn * 32 + nf * 16 + lq;
            float bcol = BIAS_ROW ? 0.f : bias[ncol];
#pragma unroll
            for (int j = 0; j < 4; j++) {
                int mrow = m0 + wm * 32 + mf * 16 + 4 * g + j;
                float v = acc[mf][nf][j] + (BIAS_ROW ? bias[mrow] : bcol);
                if (GELU) v = 0.5f * v * (1.f + erff(v * 0.70710678118654752f));
                C[(size_t)mrow * N + ncol] = f2bu(v);
            }
        }
    }
}

// =========================== MFMA flash attention ===========================
// grid 256: xcd=bid&7 -> (head = xcd>>1, key-split s = xcd&1), qblk = bid>>3.
// block: 512 thr = 8 waves, each wave 16 queries; keys [s*2048, s*2048+2048).
// Stores UNNORMALIZED O (bf16) + per-(head,query) (m,l) f32 partials.
__global__ __launch_bounds__(512, 2) void attn_mfma(
    const ushort_t* __restrict__ Qb,   // [4096][512] (cols = h*128+d)
    const ushort_t* __restrict__ Kb,   // [4096][512]
    const ushort_t* __restrict__ Vtb,  // [768][4096] (rows = h*192+vd)
    const int* __restrict__ batch_h, const int* __restrict__ batch_p,
    ushort_t* __restrict__ Opart,      // [2][4][4096][192] bf16
    float* __restrict__ ml)            // [2][4][4096][2] f32
{
    const int bid = blockIdx.x;
    const int xcd = bid & 7;
    const int h = xcd >> 1;
    const int s = xcd & 1;
    const int n0 = (bid >> 3) * 128;

    __shared__ ushort_t Kt[2][64 * 128];
    __shared__ ushort_t Vt[2][192 * 64];
    __shared__ int bps[2][64];
    __shared__ ushort_t Pl[8][16 * 72];

    const int t = threadIdx.x;
    const int w = t >> 6;
    const int lane = t & 63;
    const int lq = lane & 15;
    const int g = lane >> 4;
    const float scale = 0.08838834764831845f;  // 1/sqrt(128)

    short8 qf[4];
    {
        const ushort_t* qrow = Qb + (size_t)(n0 + w * 16 + lq) * 512 + h * 128;
#pragma unroll
        for (int ks = 0; ks < 4; ks++)
            qf[ks] = *(const short8*)(qrow + ks * 32 + g * 8);
    }
    const int bhq = batch_h[n0 + w * 16 + lq];

    f32x4 Ofr[12];
#pragma unroll
    for (int nt = 0; nt < 12; nt++) Ofr[nt] = (f32x4){0.f, 0.f, 0.f, 0.f};
    float m_run = -1e30f, l_run = 0.f;

    const char* Kg = (const char*)Kb;
    const char* Vg = (const char*)Vtb;
    const int kbase = s * 2048;

    auto STAGE = [&](int buf, int m0k) {
        // K tile 64 rows x 256B -> 16 insts, 2 per wave
#pragma unroll
        for (int jj = 0; jj < 2; jj++) {
            int j = w * 2 + jj;
            int r = j * 4 + (lane >> 4);
            int c = (lane & 15) * 16;
            gl_lds16(Kg + (size_t)(m0k + r) * 1024 + h * 256 + (c ^ ((r & 7) << 4)),
                     (void*)&Kt[buf][j * 512]);
        }
        // V tile 192 rows x 128B -> 24 insts, 3 per wave
#pragma unroll
        for (int jj = 0; jj < 3; jj++) {
            int j = w * 3 + jj;
            int r = j * 8 + (lane >> 3);
            int c = (lane & 7) * 16;
            gl_lds16(Vg + ((size_t)(h * 192 + r) * NP_N + m0k) * 2 + (c ^ ((r & 7) << 4)),
                     (void*)&Vt[buf][j * 512]);
        }
        if (w == 0) gl_lds4(batch_p + m0k + lane, (void*)&bps[buf][0]);
    };

    STAGE(0, kbase);
    __syncthreads();
    int cur = 0;

    for (int tile = 0; tile < 32; tile++) {
        if (tile + 1 < 32) STAGE(cur ^ 1, kbase + (tile + 1) * 64);

        // ---- S^T = K·Q^T ----
        f32x4 S[4];
#pragma unroll
        for (int mt = 0; mt < 4; mt++) S[mt] = (f32x4){0.f, 0.f, 0.f, 0.f};
        const char* Kbase = (const char*)&Kt[cur][0];
        const int swz = (lq & 7) << 4;
#pragma unroll
        for (int mt = 0; mt < 4; mt++) {
            int r = mt * 16 + lq;
#pragma unroll
            for (int ks = 0; ks < 4; ks++) {
                short8 kf = *(const short8*)(Kbase + r * 256 + ((ks * 64 + g * 16) ^ swz));
                S[mt] = __builtin_amdgcn_mfma_f32_16x16x32_bf16(kf, qf[ks], S[mt], 0, 0, 0);
            }
        }

        // ---- mask + scale + online softmax (column q = lq) ----
        int4 bp4[4];
#pragma unroll
        for (int mt = 0; mt < 4; mt++)
            bp4[mt] = *(const int4*)&bps[cur][16 * mt + 4 * g];

        float mx = -1e30f;
#pragma unroll
        for (int mt = 0; mt < 4; mt++) {
            float v0 = (bp4[mt].x == bhq) ? -1e10f : S[mt][0] * scale;
            float v1 = (bp4[mt].y == bhq) ? -1e10f : S[mt][1] * scale;
            float v2 = (bp4[mt].z == bhq) ? -1e10f : S[mt][2] * scale;
            float v3 = (bp4[mt].w == bhq) ? -1e10f : S[mt][3] * scale;
            S[mt][0] = v0; S[mt][1] = v1; S[mt][2] = v2; S[mt][3] = v3;
            mx = fmaxf(mx, fmaxf(fmaxf(v0, v1), fmaxf(v2, v3)));
        }
        mx = fmaxf(mx, __shfl_xor(mx, 16));
        mx = fmaxf(mx, __shfl_xor(mx, 32));

        float m_new = fmaxf(m_run, mx);
        float rsum = 0.f;
#pragma unroll
        for (int mt = 0; mt < 4; mt++) {
            float e0 = __expf(S[mt][0] - m_new);
            float e1 = __expf(S[mt][1] - m_new);
            float e2 = __expf(S[mt][2] - m_new);
            float e3 = __expf(S[mt][3] - m_new);
            rsum += (e0 + e1) + (e2 + e3);
            uint2 pw;
            pw.x = pkbf(e0, e1);
            pw.y = pkbf(e2, e3);
            *(uint2*)((char*)&Pl[w][0] + lq * 144 + mt * 32 + g * 8) = pw;
        }
        rsum += __shfl_xor(rsum, 16);
        rsum += __shfl_xor(rsum, 32);

        if (__all(mx <= m_run)) {
            l_run += rsum;
        } else {
            float f = __expf(m_run - m_new);
            l_run = l_run * f + rsum;
            m_run = m_new;
            float fr0 = __shfl(f, 4 * g + 0);
            float fr1 = __shfl(f, 4 * g + 1);
            float fr2 = __shfl(f, 4 * g + 2);
            float fr3 = __shfl(f, 4 * g + 3);
#pragma unroll
            for (int nt = 0; nt < 12; nt++) {
                Ofr[nt][0] *= fr0; Ofr[nt][1] *= fr1;
                Ofr[nt][2] *= fr2; Ofr[nt][3] *= fr3;
            }
        }

        // ---- O += P·V ----
        const char* Vbase = (const char*)&Vt[cur][0];
#pragma unroll
        for (int ks = 0; ks < 2; ks++) {
            short8 pf = *(const short8*)((const char*)&Pl[w][0] + lq * 144 + ks * 64 + g * 16);
#pragma unroll
            for (int nt = 0; nt < 12; nt++) {
                int vd = nt * 16 + lq;
                short8 vf = *(const short8*)(Vbase + vd * 128 + ((ks * 64 + g * 16) ^ swz));
                Ofr[nt] = __builtin_amdgcn_mfma_f32_16x16x32_bf16(pf, vf, Ofr[nt], 0, 0, 0);
            }
        }

        __syncthreads();
        cur ^= 1;
    }

    // ---- epilogue: store raw partials ----
    const size_t qpl = (size_t)(s * 4 + h) * 4096;
#pragma unroll
    for (int nt = 0; nt < 12; nt++) {
        int vd = nt * 16 + lq;
#pragma unroll
        for (int j = 0; j < 4; j++) {
            int q = n0 + w * 16 + 4 * g + j;
            Opart[(qpl + q) * 192 + vd] = f2bu(Ofr[nt][j]);
        }
    }
    if (lane < 16) {
        int q = n0 + w * 16 + lane;
        ml[(qpl + q) * 2 + 0] = m_run;
        ml[(qpl + q) * 2 + 1] = l_run;
    }
}

// ============== combine key-split partials + build feats tail ==============
__global__ __launch_bounds__(256) void combine_feats(
    const ushort_t* __restrict__ Opart, const float* __restrict__ ml,
    const float* __restrict__ lhs_h, ushort_t* __restrict__ feats)
{
    const int t = threadIdx.x;
#pragma unroll
    for (int i = 0; i < 4; i++) {
        int q = blockIdx.x * 4 + i;
#pragma unroll
        for (int it = 0; it < 3; it++) {
            int c = t + it * 256;
            int h = c / 192, vd = c - h * 192;
            size_t i0 = (size_t)h * 4096 + q;
            size_t i1 = (size_t)(4 + h) * 4096 + q;
            float m0 = ml[i0 * 2], l0 = ml[i0 * 2 + 1];
            float m1 = ml[i1 * 2], l1 = ml[i1 * 2 + 1];
            float m = fmaxf(m0, m1);
            float e0 = __expf(m0 - m), e1 = __expf(m1 - m);
            float linv = 1.f / (l0 * e0 + l1 * e1);
            float O = (b2f(Opart[i0 * 192 + vd]) * e0 + b2f(Opart[i1 * 192 + vd]) * e1) * linv;
            feats[(size_t)q * 1280 + 512 + c] = f2bu(lhs_h[(size_t)q * 768 + c] - O);
        }
    }
}

// ================= h2 = h1 @ W2 (f32) + LayerNorm(128) ======================
__global__ __launch_bounds__(256) void h2_ln(
    const ushort_t* __restrict__ h1, const float* __restrict__ W2,
    const float* __restrict__ ln_g, const float* __restrict__ ln_b,
    float* __restrict__ h2out)
{
    const int n0 = blockIdx.x * 8;
    const int t = threadIdx.x;
    __shared__ float h1s[8][256];
    __shared__ float h2s[8][128];

#pragma unroll
    for (int i = 0; i < 8; i++) {
        int idx = t + i * 256; int r = idx >> 8, c = idx & 255;
        h1s[r][c] = b2f(h1[(size_t)(n0 + r) * 256 + c]);
    }
    __syncthreads();

    {
        int o2 = t & 127, gq = t >> 7;
        float acc[4] = {};
        for (int k4 = 0; k4 < 64; k4++) {
            float w0 = W2[(size_t)(k4 * 4 + 0) * 128 + o2];
            float w1 = W2[(size_t)(k4 * 4 + 1) * 128 + o2];
            float w2 = W2[(size_t)(k4 * 4 + 2) * 128 + o2];
            float w3 = W2[(size_t)(k4 * 4 + 3) * 128 + o2];
#pragma unroll
            for (int q = 0; q < 4; q++) {
                float4 hh = *(const float4*)&h1s[gq * 4 + q][k4 * 4];
                acc[q] += hh.x * w0 + hh.y * w1 + hh.z * w2 + hh.w * w3;
            }
        }
#pragma unroll
        for (int q = 0; q < 4; q++) h2s[gq * 4 + q][o2] = acc[q];
    }
    __syncthreads();

    {
        int wv = t >> 6, lane = t & 63;
#pragma unroll
        for (int s = 0; s < 2; s++) {
            int nd = wv * 2 + s;
            float x0 = h2s[nd][lane], x1 = h2s[nd][lane + 64];
            float sum = x0 + x1;
#pragma unroll
            for (int off = 32; off; off >>= 1) sum += __shfl_xor(sum, off);
            float mu = sum * (1.f / 128.f);
            float d0 = x0 - mu, d1 = x1 - mu;
            float s2 = d0 * d0 + d1 * d1;
#pragma unroll
            for (int off = 32; off; off >>= 1) s2 += __shfl_xor(s2, off);
            float rstd = rsqrtf(s2 * (1.f / 128.f) + 1e-5f);
            size_t base = (size_t)(n0 + nd) * 128;
            h2out[base + lane]      = d0 * rstd * ln_g[lane] + ln_b[lane];
            h2out[base + lane + 64] = d1 * rstd * ln_g[lane + 64] + ln_b[lane + 64];
        }
    }
}

// ----------------------- segment ranges (batch ids sorted) -----------------
__global__ void ranges_kernel(const int* __restrict__ bh, int* __restrict__ lo,
                              int Nn, int Bn)
{
    int n = blockIdx.x * blockDim.x + threadIdx.x;
    if (n >= Nn) return;
    int b = bh[n];
    int prev = (n == 0) ? -1 : bh[n - 1];
    for (int bb = prev + 1; bb <= b; bb++) lo[bb] = n;
    if (n == Nn - 1) for (int bb = b + 1; bb <= Bn; bb++) lo[bb] = Nn;
}

// ----------------------- pool (mean per graph) + classifier ----------------
__global__ __launch_bounds__(128) void pool_cls(
    const float* __restrict__ h2, const int* __restrict__ lo,
    const float* __restrict__ Wc, const float* __restrict__ bc,
    float* __restrict__ out)
{
    int b = blockIdx.x, t = threadIdx.x;
    int s = lo[b], e = lo[b + 1];
    float acc = 0.f;
    for (int n = s; n < e; n++) acc += h2[(size_t)n * 128 + t];
    float pooled = acc / fmaxf((float)(e - s), 1.f);
    __shared__ float red[128];
    for (int c = 0; c < 3; c++) {
        red[t] = pooled * Wc[t * 3 + c];
        __syncthreads();
        for (int off = 64; off > 0; off >>= 1) {
            if (t < off) red[t] += red[t + off];
            __syncthreads();
        }
        if (t == 0) out[b * 3 + c] = red[0] + bc[c];
        __syncthreads();
    }
}

// ---------------------------------------------------------------------------
extern "C" void kernel_launch(void* const* d_in, const int* in_sizes, int n_in,
                              void* d_out, int out_size, void* d_ws, size_t ws_size,
                              hipStream_t stream)
{
    const float* ctx_p  = (const float*)d_in[0];
    const float* ctx_h  = (const float*)d_in[1];
    const float* lhs_p  = (const float*)d_in[2];
    const float* lhs_h  = (const float*)d_in[3];
    const int*   batch_p = (const int*)d_in[4];
    const int*   batch_h = (const int*)d_in[5];
    const float* Wq = (const float*)d_in[6];
    const float* bq = (const float*)d_in[7];
    const float* Wk = (const float*)d_in[8];
    const float* bk = (const float*)d_in[9];
    const float* Wv = (const float*)d_in[10];
    const float* bv = (const float*)d_in[11];
    const float* W1 = (const float*)d_in[12];
    const float* b1 = (const float*)d_in[13];
    const float* W2 = (const float*)d_in[14];
    const float* ln_g = (const float*)d_in[15];
    const float* ln_b = (const float*)d_in[16];
    const float* Wc = (const float*)d_in[17];
    const float* bc = (const float*)d_in[18];
    float* out = (float*)d_out;

    // ---- workspace layout (ushort units unless noted) ----
    ushort_t* u = (ushort_t*)d_ws;
    ushort_t* ctxh_bf = u;                       // 2097152
    ushort_t* ctxp_bf = ctxh_bf + 2097152;       // 2097152
    ushort_t* lhsp_bf = ctxp_bf + 2097152;       // 3145728
    ushort_t* Opart   = ctxh_bf;                 // ALIAS: 6291456 (over ctxh/ctxp/lhsp)
    ushort_t* Wqt  = lhsp_bf + 3145728;          // 262144
    ushort_t* Wkt  = Wqt + 262144;               // 262144
    ushort_t* Wvt  = Wkt + 262144;               // 589824
    ushort_t* W1t  = Wvt + 589824;               // 327680
    ushort_t* Qb   = W1t + 327680;               // 2097152
    ushort_t* Kb   = Qb + 2097152;               // 2097152
    ushort_t* Vtb  = Kb + 2097152;               // 3145728
    ushort_t* feats = Vtb + 3145728;             // 5242880
    ushort_t* h1   = feats + 5242880;            // 1048576
    float* fbase = (float*)(h1 + 1048576);
    float* ml   = fbase;                         // 131072 f32
    float* h2   = ml + 131072;                   // 524288 f32
    float* bqp  = h2 + 524288;                   // 512
    float* bkp  = bqp + 512;                     // 512
    int*   lo   = (int*)(bkp + 512);             // 33

    convert_all<<<864, 256, 0, stream>>>(
        ctx_h, ctx_p, lhs_p, Wq, Wk, Wv, W1, bq, bk,
        ctxh_bf, ctxp_bf, lhsp_bf, feats, Wqt, Wkt, Wvt, W1t, bqp, bkp);

    gemm_bf<0, 0><<<dim3(8, 64), 256, 0, stream>>>(ctxh_bf, Wqt, bqp, Qb, NH_N, 512, 512);
    gemm_bf<0, 0><<<dim3(8, 64), 256, 0, stream>>>(ctxp_bf, Wkt, bkp, Kb, NP_N, 512, 512);
    gemm_bf<1, 0><<<dim3(64, 12), 256, 0, stream>>>(Wvt, lhsp_bf, bv, Vtb, 768, NP_N, 768);

    attn_mfma<<<256, 512, 0, stream>>>(Qb, Kb, Vtb, batch_h, batch_p, Opart, ml);

    combine_feats<<<1024, 256, 0, stream>>>(Opart, ml, lhs_h, feats);

    gemm_bf<0, 1><<<dim3(4, 64), 256, 0, stream>>>(feats, W1t, b1, h1, NH_N, 256, 1280);

    h2_ln<<<512, 256, 0, stream>>>(h1, W2, ln_g, ln_b, h2);
    ranges_kernel<<<16, 256, 0, stream>>>(batch_h, lo, NH_N, B_N);
    pool_cls<<<B_N, 128, 0, stream>>>(h2, lo, Wc, bc, out);
}